// Round 2
// baseline (77.956 us; speedup 1.0000x reference)
//
#include <hip/hip_runtime.h>

#define NBINS 100
#define PWL_VMIN -5.0f
#define PWL_VMAX 5.0f

// ---------------------------------------------------------------------------
// Fused kernel: every block builds the tiny tables (101 expf + sequential
// 100-step cumsum to match jnp.cumsum rounding) in LDS, then processes its
// grid-stride share of eps as float4. Per-thread float4 loads are issued
// BEFORE the table build so HBM latency hides the serial scan.
// Grid is sized so each thread handles at most 2 float4s (n4 < 2*stride),
// with a safety loop for any leftover.
// ---------------------------------------------------------------------------
__global__ __launch_bounds__(256) void pwl_fused_kernel(
    const float* __restrict__ eps,     // [N]
    const float* __restrict__ p,       // [NBINS+1]
    const float* __restrict__ b,       // [1]
    const float* __restrict__ points,  // [NBINS]
    float* __restrict__ out,           // [N]
    int n4)                            // N/4 float4 groups
{
    __shared__ float s_pts[NBINS];
    __shared__ float s_k[NBINS + 1];
    __shared__ float s_db[NBINS];

    const int t      = threadIdx.x;
    const int tid    = blockIdx.x * blockDim.x + t;
    const int stride = gridDim.x * blockDim.x;

    const float4* __restrict__ in4  = reinterpret_cast<const float4*>(eps);
    float4* __restrict__       out4 = reinterpret_cast<float4*>(out);

    // --- prefetch this thread's elements (hides HBM latency under table build)
    const int i0 = tid;
    const int i1 = tid + stride;
    float4 e0, e1;
    const bool h0 = (i0 < n4);
    const bool h1 = (i1 < n4);
    if (h0) e0 = in4[i0];
    if (h1) e1 = in4[i1];

    // --- stage tables
    if (t < NBINS)  s_pts[t] = points[t];
    if (t <= NBINS) s_k[t]   = expf(p[t]) + 0.001f;
    __syncthreads();
    if (t == 0) {
        const float int_length = (PWL_VMAX - PWL_VMIN) / (float)(NBINS - 1);
        const float b0 = b[0];
        float acc = 0.0f;                 // prefix[0] = 0
        s_db[0] = b0;                     // delta_bias[0] = b
        for (int i = 1; i < NBINS; ++i) {
            acc += int_length * s_k[i];   // delta_h[i-1] = int_length * k[i]
            s_db[i] = b0 + acc;           // match reference: b + prefix
        }
    }
    __syncthreads();

    const float inv_step = (float)(NBINS - 1) / (PWL_VMAX - PWL_VMIN);

    auto process = [&](float4 e4) -> float4 {
        float ev[4] = {e4.x, e4.y, e4.z, e4.w};
        float r[4];
#pragma unroll
        for (int j = 0; j < 4; ++j) {
            const float e = ev[j];
            // arithmetic guess for index = #(points <= e), then exact fixup
            int idx = (int)floorf((e - PWL_VMIN) * inv_step) + 1;
            idx = max(0, min(idx, NBINS));
            while (idx < NBINS && s_pts[idx] <= e) ++idx;   // <=1 step
            while (idx > 0 && s_pts[idx - 1] > e) --idx;    // <=1 step
            const int si = max(idx - 1, 0);
            r[j] = (e - s_pts[si]) * s_k[idx] + s_db[si];
        }
        return make_float4(r[0], r[1], r[2], r[3]);
    };

    if (h0) out4[i0] = process(e0);
    if (h1) out4[i1] = process(e1);

    // safety: handle any elements beyond 2*stride (none for N=4M with this grid)
    for (int i = tid + 2 * stride; i < n4; i += stride) {
        out4[i] = process(in4[i]);
    }
}

// ---------------------------------------------------------------------------
extern "C" void kernel_launch(void* const* d_in, const int* in_sizes, int n_in,
                              void* d_out, int out_size, void* d_ws, size_t ws_size,
                              hipStream_t stream)
{
    const float* eps    = (const float*)d_in[0];  // [4M, 1]
    const float* p      = (const float*)d_in[1];  // [101]
    const float* b      = (const float*)d_in[2];  // [1]
    const float* points = (const float*)d_in[3];  // [1, 100]
    float* out          = (float*)d_out;          // [4M, 1]

    const int n  = out_size;        // 4,000,000 (divisible by 4)
    const int n4 = n / 4;
    const int block = 256;
    int grid = 2048;                // 524288 threads -> <=2 float4 per thread
    pwl_fused_kernel<<<grid, block, 0, stream>>>(eps, p, b, points, out, n4);
}